// Round 6
// baseline (427.503 us; speedup 1.0000x reference)
//
#include <hip/hip_runtime.h>

#define DEG 16
#define TT 16
#define MM 8
#define NL 4           /* lanes per problem */
#define NNR 4          /* regular rows per lane: lane h owns neighbors [h*4, h*4+4) */

#define C_SCALE 14.426950408889634f   /* log2(e)/eps, eps=0.1 */
#define INV_C   0.069314718055994530f /* 1/C_SCALE : Mh = hp - INV_C*log2(E) */
#define PP (1.0f / 17.0f)
#define QQ 0.125f

#define TF_STRIDE 129   /* float4 row pad: 516 dwords % 32 == 4 -> 2-way max (free) */
#define C2_STRIDE 65    /* float row pad: 65 % 32 == 1 -> conflict-free */

// ---------------- kernel A: P = x @ tf_flat^T  [n_nodes x 128], sqn = ||x_i||^2 ----
__global__ __launch_bounds__(256) void precomp(const float* __restrict__ x,
                                               const float* __restrict__ tf,
                                               float* __restrict__ P,
                                               float* __restrict__ sqn) {
  __shared__ float4 tf_lds[TT * TF_STRIDE];
  const float4* tf4g = (const float4*)tf;
  for (int i = threadIdx.x; i < TT * MM * 16; i += 256) {
    int tt = i >> 7, rem = i & 127;
    tf_lds[tt * TF_STRIDE + rem] = tf4g[i];
  }
  __syncthreads();

  int gid = blockIdx.x * 256 + (int)threadIdx.x;
  int i = gid >> 4, c = gid & 15;         // node i, template-chunk c (8 cols)
  const float4* x4 = (const float4*)x + (size_t)i * 16;
  const float4* tfl = &tf_lds[c * TF_STRIDE];

  float acc[MM];
  float sq = 0.f;
#pragma unroll
  for (int m = 0; m < MM; ++m) acc[m] = 0.f;
  for (int k = 0; k < 16; ++k) {
    float4 xl = x4[k];
    sq += xl.x * xl.x + xl.y * xl.y + xl.z * xl.z + xl.w * xl.w;
#pragma unroll
    for (int m = 0; m < MM; ++m) {
      float4 tv = tfl[m * 16 + k];
      acc[m] += xl.x * tv.x + xl.y * tv.y + xl.z * tv.z + xl.w * tv.w;
    }
  }
  float4* Pr = (float4*)(P + (size_t)i * 128 + c * 8);
  Pr[0] = make_float4(acc[0], acc[1], acc[2], acc[3]);
  Pr[1] = make_float4(acc[4], acc[5], acc[6], acc[7]);
  if (c == 0) sqn[i] = sq;
}

// ---------------- kernel B: 4 lanes per (node,template) FGW problem ----------------
// State sized to fit the 128-VGPR budget the backend insists on (rounds 3-5 all
// spilled at ~160 live floats). 4-lane group = xor masks 16 & 32 within a wave64.
__global__ __launch_bounds__(256)
void ltfgw_main(const float* __restrict__ P,
                const float* __restrict__ sqn,
                const int* __restrict__ dstRow,
                const float* __restrict__ c2g,
                float* __restrict__ out) {
  __shared__ float c2_lds[TT * C2_STRIDE];
  for (int i = threadIdx.x; i < TT * MM * MM; i += 256) {
    int tt = i >> 6, rem = i & 63;
    c2_lds[tt * C2_STRIDE + rem] = c2g[i];
  }
  __syncthreads();

  const int gid = blockIdx.x * 256 + (int)threadIdx.x;
  const int t = gid & 15;
  const int h = (gid >> 4) & 3;           // quarter: owns regular rows [h*4, h*4+4)
  const int node = gid >> 6;
  const float hmask = (h == 0) ? 1.f : 0.f;
  const float* c2l = &c2_lds[t * C2_STRIDE];

  // T0b[j] = 0.5*(16/17 + bq[j]) - 0.125*csum[j] ;  T1b[j] = 0.5*(1/17 + bq[j])
  float T0b[MM], T1b[MM];
#pragma unroll
  for (int j = 0; j < MM; ++j) {
    float s = 0.f, cs = 0.f;
#pragma unroll
    for (int k = 0; k < MM; ++k) {
      float vjk = c2l[j * MM + k];
      s += vjk * vjk;
      cs += c2l[k * MM + j];
    }
    float bq = s * 0.125f;
    T0b[j] = 0.5f * (16.f / 17.f + bq) - 0.125f * cs;
    T1b[j] = 0.5f * (1.f / 17.f + bq);
  }

  // ---- gather my rows of P, build row-normalized kernel factor E ----
  const float4* Pb = (const float4*)P;
  const int* nb = dstRow + node * DEG + h * NNR;
  float Ereg[NNR][MM], hp[NNR];
  float E0[MM], hp0;
#pragma unroll
  for (int k = 0; k < NNR; ++k) {
    int idx = nb[k];
    float4 p0 = Pb[(size_t)idx * 32 + t * 2];
    float4 p1 = Pb[(size_t)idx * 32 + t * 2 + 1];
    float pv[MM] = {p0.x, p0.y, p0.z, p0.w, p1.x, p1.y, p1.z, p1.w};
    float pm = pv[0];
#pragma unroll
    for (int j = 1; j < MM; ++j) pm = fmaxf(pm, pv[j]);
#pragma unroll
    for (int j = 0; j < MM; ++j)
      Ereg[k][j] = __builtin_amdgcn_exp2f(C_SCALE * (pv[j] - pm));
    hp[k] = 0.5f * (sqn[idx] + 1.0f) - pm;   // Mh[k][j] = hp[k] - INV_C*log2(E)
  }
  {  // center row (lane h=0 keeps it; others get E0 = 0, branch-free)
    float4 p0 = Pb[(size_t)node * 32 + t * 2];
    float4 p1 = Pb[(size_t)node * 32 + t * 2 + 1];
    float pv[MM] = {p0.x, p0.y, p0.z, p0.w, p1.x, p1.y, p1.z, p1.w};
    float pm = pv[0];
#pragma unroll
    for (int j = 1; j < MM; ++j) pm = fmaxf(pm, pv[j]);
#pragma unroll
    for (int j = 0; j < MM; ++j)
      E0[j] = hmask * __builtin_amdgcn_exp2f(C_SCALE * (pv[j] - pm));
    hp0 = 0.5f * (sqn[node] + 1.0f) - pm;
  }

  // G0 = p q^T: row-0 marginal; col-sums of rows>=1 are 0.125 - g0_
  float g0_[MM];
#pragma unroll
  for (int j = 0; j < MM; ++j) g0_[j] = 1.f / 136.f;

  float u0, ureg[NNR], v_[MM], e0c[MM], cf1[MM];

  for (int outer = 0; outer < 4; ++outer) {
#pragma unroll
    for (int j = 0; j < MM; ++j) {
      float gd = 0.f;
#pragma unroll
      for (int k = 0; k < MM; ++k) gd += g0_[k] * c2l[k * MM + j];
      e0c[j] = __builtin_amdgcn_exp2f(-C_SCALE * (T0b[j] + gd)) * E0[j];
      cf1[j] = __builtin_amdgcn_exp2f(-C_SCALE * (T1b[j] - gd));
      v_[j] = 1.f;
    }
    // stabilized plain Sinkhorn; 4-lane butterfly closes column reductions
    for (int it = 0; it < 10; ++it) {
      float w1[MM];
      float kv0 = (h == 0) ? 0.f : 1.f;     // lanes h!=0: e0c=0 -> u0 finite, unused
#pragma unroll
      for (int j = 0; j < MM; ++j) { w1[j] = cf1[j] * v_[j]; kv0 += e0c[j] * v_[j]; }
      u0 = PP * __builtin_amdgcn_rcpf(kv0);
#pragma unroll
      for (int k = 0; k < NNR; ++k) {
        float kv = 0.f;
#pragma unroll
        for (int j = 0; j < MM; ++j) kv += Ereg[k][j] * w1[j];
        ureg[k] = PP * __builtin_amdgcn_rcpf(kv);
      }
#pragma unroll
      for (int j = 0; j < MM; ++j) {
        float z = 0.f;
#pragma unroll
        for (int k = 0; k < NNR; ++k) z += Ereg[k][j] * ureg[k];
        float part = cf1[j] * z + e0c[j] * u0;
        part += __shfl_xor(part, 16);
        part += __shfl_xor(part, 32);
        v_[j] = QQ * __builtin_amdgcn_rcpf(part);
      }
    }
    // row-0 marginal of G for next linearization (only lane0's e0c*u0 nonzero)
#pragma unroll
    for (int j = 0; j < MM; ++j) {
      float e0u = e0c[j] * u0;
      e0u += __shfl_xor(e0u, 16);
      e0u += __shfl_xor(e0u, 32);
      g0_[j] = v_[j] * e0u;
    }
  }

  // ---------------- final fgw = sum G .* (Mh + 0.5*tens(G)) ----------------
  float fg = 0.f;
  {
    float w1f[MM], T0p[MM], tens1 = 0.f;
#pragma unroll
    for (int j = 0; j < MM; ++j) {
      float gd = 0.f;
#pragma unroll
      for (int k = 0; k < MM; ++k) gd += g0_[k] * c2l[k * MM + j];
      T0p[j] = T0b[j] + gd;
      float T1p = T1b[j] - gd;
      tens1 += (0.125f - g0_[j]) * T1p;
      w1f[j] = cf1[j] * v_[j];
    }
    // my regular rows: G[r][j] = ureg*Ereg*w1f ; Mh = hp - INV_C*log2(E)
#pragma unroll
    for (int k = 0; k < NNR; ++k) {
      float racc = 0.f;
#pragma unroll
      for (int j = 0; j < MM; ++j) {
        float e = Ereg[k][j];
        float mh = hp[k] - INV_C * __builtin_amdgcn_logf(fmaxf(e, 1e-30f));
        racc += e * w1f[j] * mh;
      }
      fg += ureg[k] * racc;
    }
    // lane0-only: center row + structure-constant part over rows>=1
    float r0 = 0.f;
#pragma unroll
    for (int j = 0; j < MM; ++j) {
      float mh0 = hp0 - INV_C * __builtin_amdgcn_logf(fmaxf(E0[j], 1e-30f));
      r0 += g0_[j] * (mh0 + T0p[j]);
    }
    fg += hmask * (r0 + tens1);
  }
  fg += __shfl_xor(fg, 16);
  fg += __shfl_xor(fg, 32);
  if (h == 0) out[node * TT + t] = fg;
}

extern "C" void kernel_launch(void* const* d_in, const int* in_sizes, int n_in,
                              void* d_out, int out_size, void* d_ws, size_t ws_size,
                              hipStream_t stream) {
  const float* x  = (const float*)d_in[0];
  const int*   ei = (const int*)d_in[1];
  const float* tf = (const float*)d_in[2];
  const float* c2 = (const float*)d_in[3];
  const int* dstRow = ei + (in_sizes[1] / 2);   // row 1 of edge_index [2, N*DEG]
  int n_nodes = in_sizes[0] / 64;               // 20000

  float* P   = (float*)d_ws;                    // [n_nodes][128]
  float* sqn = P + (size_t)n_nodes * 128;       // [n_nodes]
  float* out = (float*)d_out;

  int threadsA = n_nodes * 16;
  precomp<<<(threadsA + 255) / 256, 256, 0, stream>>>(x, tf, P, sqn);
  int lanesB = out_size * NL;                   // 4 lanes per problem
  ltfgw_main<<<(lanesB + 255) / 256, 256, 0, stream>>>(P, sqn, dstRow, c2, out);
}

// Round 8
// 290.654 us; speedup vs baseline: 1.4708x; 1.4708x over previous
//
#include <hip/hip_runtime.h>

#define DEG 16
#define TT 16
#define MM 8
#define NNR 8          /* regular rows per lane: lane h owns neighbors [h*8, h*8+8) */

#define C_SCALE 14.426950408889634f   /* log2(e)/eps, eps=0.1 */
#define PP (1.0f / 17.0f)
#define QVP 2.125f                    /* (1/8) / (1/17) = 17/8 */

#define TF_STRIDE 129   /* float4 row pad: 516 dwords % 32 == 4 -> 2-way max (free) */
#define C2_STRIDE 65    /* float row pad: 65 % 32 == 1 -> conflict-free */

// ---------------- kernel A: P = x @ tf_flat^T  [n_nodes x 128], sqn = ||x_i||^2 ----
__global__ __launch_bounds__(256) void precomp(const float* __restrict__ x,
                                               const float* __restrict__ tf,
                                               float* __restrict__ P,
                                               float* __restrict__ sqn) {
  __shared__ float4 tf_lds[TT * TF_STRIDE];
  const float4* tf4g = (const float4*)tf;
  for (int i = threadIdx.x; i < TT * MM * 16; i += 256) {
    int tt = i >> 7, rem = i & 127;
    tf_lds[tt * TF_STRIDE + rem] = tf4g[i];
  }
  __syncthreads();

  int gid = blockIdx.x * 256 + (int)threadIdx.x;
  int i = gid >> 4, c = gid & 15;         // node i, template-chunk c (8 cols)
  const float4* x4 = (const float4*)x + (size_t)i * 16;
  const float4* tfl = &tf_lds[c * TF_STRIDE];

  float acc[MM];
  float sq = 0.f;
#pragma unroll
  for (int m = 0; m < MM; ++m) acc[m] = 0.f;
  for (int k = 0; k < 16; ++k) {
    float4 xl = x4[k];
    sq += xl.x * xl.x + xl.y * xl.y + xl.z * xl.z + xl.w * xl.w;
#pragma unroll
    for (int m = 0; m < MM; ++m) {
      float4 tv = tfl[m * 16 + k];
      acc[m] += xl.x * tv.x + xl.y * tv.y + xl.z * tv.z + xl.w * tv.w;
    }
  }
  float4* Pr = (float4*)(P + (size_t)i * 128 + c * 8);
  Pr[0] = make_float4(acc[0], acc[1], acc[2], acc[3]);
  Pr[1] = make_float4(acc[4], acc[5], acc[6], acc[7]);
  if (c == 0) sqn[i] = sq;
}

// ---------------- kernel B: 2 lanes per (node,template) FGW problem ----------------
// Column cost factors folded multiplicatively into Ereg (exact); PP folded out of
// the inner loop; Mh reconstructed by end re-gather. Live state ~117 floats ->
// fits the register budget without spill (round 4/5 spilled at ~160).
__global__ __launch_bounds__(256)
void ltfgw_main(const float* __restrict__ P,
                const float* __restrict__ sqn,
                const int* __restrict__ dstRow,
                const float* __restrict__ c2g,
                float* __restrict__ out) {
  __shared__ float c2_lds[TT * C2_STRIDE];
  for (int i = threadIdx.x; i < TT * MM * MM; i += 256) {
    int tt = i >> 6, rem = i & 63;
    c2_lds[tt * C2_STRIDE + rem] = c2g[i];
  }
  __syncthreads();

  const int gid = blockIdx.x * 256 + (int)threadIdx.x;
  const int t = gid & 15;
  const int h = (gid >> 4) & 1;           // half: lane pair via xor 16
  const int node = gid >> 5;
  const float hmask = (h == 0) ? 1.f : 0.f;
  const float* c2l = &c2_lds[t * C2_STRIDE];

  const float4* Pb = (const float4*)P;
  const int* nb = dstRow + node * DEG + h * NNR;

  // ---- gather my 8 rows of P, build row-normalized kernel factor E ----
  float Ereg[NNR][MM];
#pragma unroll
  for (int k = 0; k < NNR; ++k) {
    int idx = nb[k];
    float4 p0 = Pb[(size_t)idx * 32 + t * 2];
    float4 p1 = Pb[(size_t)idx * 32 + t * 2 + 1];
    float pv[MM] = {p0.x, p0.y, p0.z, p0.w, p1.x, p1.y, p1.z, p1.w};
    float pm = pv[0];
#pragma unroll
    for (int j = 1; j < MM; ++j) pm = fmaxf(pm, pv[j]);
#pragma unroll
    for (int j = 0; j < MM; ++j)
      Ereg[k][j] = __builtin_amdgcn_exp2f(C_SCALE * (pv[j] - pm));
  }
  float e0c[MM];
  {  // center row (lane0 keeps it; lane1 zeros, branch-free)
    float4 p0 = Pb[(size_t)node * 32 + t * 2];
    float4 p1 = Pb[(size_t)node * 32 + t * 2 + 1];
    float pv[MM] = {p0.x, p0.y, p0.z, p0.w, p1.x, p1.y, p1.z, p1.w};
    float pm = pv[0];
#pragma unroll
    for (int j = 1; j < MM; ++j) pm = fmaxf(pm, pv[j]);
#pragma unroll
    for (int j = 0; j < MM; ++j)
      e0c[j] = hmask * __builtin_amdgcn_exp2f(C_SCALE * (pv[j] - pm));
  }

  // ---- fold initial (outer-0) column cost factors into Ereg / e0c ----
  // gd0[j] = csum[j]/136 (uniform G0). T0 = .5*(16/17+bq) - csum/8 + gd0;
  // T1 = .5*(1/17+bq) - gd0. Row factor exp2(-C*T).
#pragma unroll
  for (int j = 0; j < MM; ++j) {
    float s = 0.f, cs = 0.f;
#pragma unroll
    for (int k = 0; k < MM; ++k) {
      float a = c2l[j * MM + k];
      s += a * a;
      cs += c2l[k * MM + j];
    }
    float bq = 0.125f * s;
    float T0 = 0.5f * (16.f / 17.f + bq) - 0.125f * cs + cs * (1.f / 136.f);
    float T1 = 0.5f * (1.f / 17.f + bq) - cs * (1.f / 136.f);
    e0c[j] *= __builtin_amdgcn_exp2f(-C_SCALE * T0);
    float cf = __builtin_amdgcn_exp2f(-C_SCALE * T1);
#pragma unroll
    for (int k = 0; k < NNR; ++k) Ereg[k][j] *= cf;
  }

  float g0_[MM];
#pragma unroll
  for (int j = 0; j < MM; ++j) g0_[j] = 1.f / 136.f;

  float v_[MM], u0, ureg[NNR];

  for (int outer = 0; outer < 4; ++outer) {
#pragma unroll
    for (int j = 0; j < MM; ++j) v_[j] = 1.f;
    // stabilized plain Sinkhorn; u' = rcp(kv) (PP folded out), v = (Q/P)*rcp(K^T u')
    for (int it = 0; it < 10; ++it) {
      float kv0 = (float)h;                 // lane1: e0c=0 -> u0 finite, unused
#pragma unroll
      for (int j = 0; j < MM; ++j) kv0 += e0c[j] * v_[j];
      u0 = __builtin_amdgcn_rcpf(kv0);
#pragma unroll
      for (int k = 0; k < NNR; ++k) {
        float kv = 0.f;
#pragma unroll
        for (int j = 0; j < MM; ++j) kv += Ereg[k][j] * v_[j];
        ureg[k] = __builtin_amdgcn_rcpf(kv);
      }
      float part[MM];
#pragma unroll
      for (int j = 0; j < MM; ++j) {
        float z = e0c[j] * u0;
#pragma unroll
        for (int k = 0; k < NNR; ++k) z += Ereg[k][j] * ureg[k];
        part[j] = z;
      }
#pragma unroll
      for (int j = 0; j < MM; ++j) part[j] += __shfl_xor(part[j], 16);
#pragma unroll
      for (int j = 0; j < MM; ++j) v_[j] = QVP * __builtin_amdgcn_rcpf(part[j]);
    }
    // new row-0 marginal of G
    float g0n[MM];
#pragma unroll
    for (int j = 0; j < MM; ++j) {
      float e0u = e0c[j] * u0;
      e0u += __shfl_xor(e0u, 16);
      g0n[j] = PP * v_[j] * e0u;
    }
    if (outer < 3) {
      // re-linearize: multiply in the cost-delta column factors exp2(+/-C*dgd)
      float cf[MM];
#pragma unroll
      for (int j = 0; j < MM; ++j) {
        float d = 0.f;
#pragma unroll
        for (int k = 0; k < MM; ++k) d += (g0n[k] - g0_[k]) * c2l[k * MM + j];
        float a = C_SCALE * d;
        cf[j] = __builtin_amdgcn_exp2f(a);
        e0c[j] *= __builtin_amdgcn_exp2f(-a);
      }
#pragma unroll
      for (int k = 0; k < NNR; ++k)
#pragma unroll
        for (int j = 0; j < MM; ++j) Ereg[k][j] *= cf[j];
    }
#pragma unroll
    for (int j = 0; j < MM; ++j) g0_[j] = g0n[j];
  }

  // ---------------- final fgw = sum G .* (Mh + 0.5*tens(G)) ----------------
  float T0p[MM];
  float tens1 = 0.f;
#pragma unroll
  for (int j = 0; j < MM; ++j) {
    float s = 0.f, cs = 0.f, gd = 0.f;
#pragma unroll
    for (int k = 0; k < MM; ++k) {
      float a = c2l[j * MM + k];
      s += a * a;
      cs += c2l[k * MM + j];
      gd += g0_[k] * c2l[k * MM + j];
    }
    float bq = 0.125f * s;
    T0p[j] = 0.5f * (16.f / 17.f + bq) - 0.125f * cs + gd;
    float T1p = 0.5f * (1.f / 17.f + bq) - gd;
    tens1 += (0.125f - g0_[j]) * T1p;
  }
  // my regular rows: G[k][j] = PP*u'[k]*Ereg[k][j]*v[j]; Mh = hh - pv (re-gather)
  float fgr = 0.f;
#pragma unroll
  for (int k = 0; k < NNR; ++k) {
    int idx = nb[k];
    float4 p0 = Pb[(size_t)idx * 32 + t * 2];
    float4 p1 = Pb[(size_t)idx * 32 + t * 2 + 1];
    float pv[MM] = {p0.x, p0.y, p0.z, p0.w, p1.x, p1.y, p1.z, p1.w};
    float hh = 0.5f * (sqn[idx] + 1.0f);
    float racc = 0.f;
#pragma unroll
    for (int j = 0; j < MM; ++j)
      racc += Ereg[k][j] * v_[j] * (hh - pv[j]);
    fgr += ureg[k] * racc;
  }
  float fg = PP * fgr;
  {  // lane0-only: center row + structure-constant part over rows>=1
    float4 p0 = Pb[(size_t)node * 32 + t * 2];
    float4 p1 = Pb[(size_t)node * 32 + t * 2 + 1];
    float pv[MM] = {p0.x, p0.y, p0.z, p0.w, p1.x, p1.y, p1.z, p1.w};
    float hh0 = 0.5f * (sqn[node] + 1.0f);
    float r0 = 0.f;
#pragma unroll
    for (int j = 0; j < MM; ++j) r0 += g0_[j] * (hh0 - pv[j] + T0p[j]);
    fg += hmask * (r0 + tens1);
  }
  fg += __shfl_xor(fg, 16);
  if (h == 0) out[node * TT + t] = fg;
}

extern "C" void kernel_launch(void* const* d_in, const int* in_sizes, int n_in,
                              void* d_out, int out_size, void* d_ws, size_t ws_size,
                              hipStream_t stream) {
  const float* x  = (const float*)d_in[0];
  const int*   ei = (const int*)d_in[1];
  const float* tf = (const float*)d_in[2];
  const float* c2 = (const float*)d_in[3];
  const int* dstRow = ei + (in_sizes[1] / 2);   // row 1 of edge_index [2, N*DEG]
  int n_nodes = in_sizes[0] / 64;               // 20000

  float* P   = (float*)d_ws;                    // [n_nodes][128]
  float* sqn = P + (size_t)n_nodes * 128;       // [n_nodes]
  float* out = (float*)d_out;

  int threadsA = n_nodes * 16;
  precomp<<<(threadsA + 255) / 256, 256, 0, stream>>>(x, tf, P, sqn);
  int lanesB = out_size * 2;                    // 2 lanes per problem
  ltfgw_main<<<(lanesB + 255) / 256, 256, 0, stream>>>(P, sqn, dstRow, c2, out);
}

// Round 9
// 215.823 us; speedup vs baseline: 1.9808x; 1.3467x over previous
//
#include <hip/hip_runtime.h>

#define DEG 16
#define TT 16
#define MM 8
#define MM2 4          /* MM/2 packed pairs */
#define NNR 8          /* regular rows per lane: lane h owns neighbors [h*8, h*8+8) */

#define C_SCALE 14.426950408889634f   /* log2(e)/eps, eps=0.1 */
#define PP (1.0f / 17.0f)
#define QVP 2.125f                    /* (1/8) / (1/17) = 17/8 */

#define TF_STRIDE 129   /* float4 row pad: 516 dwords % 32 == 4 -> 2-way max (free) */
#define C2_STRIDE 65    /* float row pad: 65 % 32 == 1 -> conflict-free */

typedef float f32x2 __attribute__((ext_vector_type(2)));

// ---------------- kernel A: P = x @ tf_flat^T  [n_nodes x 128], sqn = ||x_i||^2 ----
__global__ __launch_bounds__(256) void precomp(const float* __restrict__ x,
                                               const float* __restrict__ tf,
                                               float* __restrict__ P,
                                               float* __restrict__ sqn) {
  __shared__ float4 tf_lds[TT * TF_STRIDE];
  const float4* tf4g = (const float4*)tf;
  for (int i = threadIdx.x; i < TT * MM * 16; i += 256) {
    int tt = i >> 7, rem = i & 127;
    tf_lds[tt * TF_STRIDE + rem] = tf4g[i];
  }
  __syncthreads();

  int gid = blockIdx.x * 256 + (int)threadIdx.x;
  int i = gid >> 4, c = gid & 15;         // node i, template-chunk c (8 cols)
  const float4* x4 = (const float4*)x + (size_t)i * 16;
  const float4* tfl = &tf_lds[c * TF_STRIDE];

  float acc[MM];
  float sq = 0.f;
#pragma unroll
  for (int m = 0; m < MM; ++m) acc[m] = 0.f;
  for (int k = 0; k < 16; ++k) {
    float4 xl = x4[k];
    sq += xl.x * xl.x + xl.y * xl.y + xl.z * xl.z + xl.w * xl.w;
#pragma unroll
    for (int m = 0; m < MM; ++m) {
      float4 tv = tfl[m * 16 + k];
      acc[m] += xl.x * tv.x + xl.y * tv.y + xl.z * tv.z + xl.w * tv.w;
    }
  }
  float4* Pr = (float4*)(P + (size_t)i * 128 + c * 8);
  Pr[0] = make_float4(acc[0], acc[1], acc[2], acc[3]);
  Pr[1] = make_float4(acc[4], acc[5], acc[6], acc[7]);
  if (c == 0) sqn[i] = sq;
}

// ---------------- kernel B: 2 lanes per (node,template) FGW problem ----------------
// Hot-loop arithmetic packed as f32x2 pairs -> v_pk_fma_f32 (VOP3P), halving VALU
// issue slots. rcp/exp2 stay scalar (trans pipe), shuffles stay DS.
__global__ __launch_bounds__(256)
void ltfgw_main(const float* __restrict__ P,
                const float* __restrict__ sqn,
                const int* __restrict__ dstRow,
                const float* __restrict__ c2g,
                float* __restrict__ out) {
  __shared__ float c2_lds[TT * C2_STRIDE];
  for (int i = threadIdx.x; i < TT * MM * MM; i += 256) {
    int tt = i >> 6, rem = i & 63;
    c2_lds[tt * C2_STRIDE + rem] = c2g[i];
  }
  __syncthreads();

  const int gid = blockIdx.x * 256 + (int)threadIdx.x;
  const int t = gid & 15;
  const int h = (gid >> 4) & 1;           // half: lane pair via xor 16
  const int node = gid >> 5;
  const float hmask = (h == 0) ? 1.f : 0.f;
  const float* c2l = &c2_lds[t * C2_STRIDE];

  const float4* Pb = (const float4*)P;
  const int* nb = dstRow + node * DEG + h * NNR;

  // ---- gather my 8 rows of P, build row-normalized kernel factor E (packed) ----
  f32x2 E2[NNR][MM2];
#pragma unroll
  for (int k = 0; k < NNR; ++k) {
    int idx = nb[k];
    float4 p0 = Pb[(size_t)idx * 32 + t * 2];
    float4 p1 = Pb[(size_t)idx * 32 + t * 2 + 1];
    float pv[MM] = {p0.x, p0.y, p0.z, p0.w, p1.x, p1.y, p1.z, p1.w};
    float pm = pv[0];
#pragma unroll
    for (int j = 1; j < MM; ++j) pm = fmaxf(pm, pv[j]);
#pragma unroll
    for (int j2 = 0; j2 < MM2; ++j2) {
      f32x2 e = {__builtin_amdgcn_exp2f(C_SCALE * (pv[2 * j2] - pm)),
                 __builtin_amdgcn_exp2f(C_SCALE * (pv[2 * j2 + 1] - pm))};
      E2[k][j2] = e;
    }
  }
  f32x2 e0c2[MM2];
  {  // center row (lane0 keeps it; lane1 zeros, branch-free)
    float4 p0 = Pb[(size_t)node * 32 + t * 2];
    float4 p1 = Pb[(size_t)node * 32 + t * 2 + 1];
    float pv[MM] = {p0.x, p0.y, p0.z, p0.w, p1.x, p1.y, p1.z, p1.w};
    float pm = pv[0];
#pragma unroll
    for (int j = 1; j < MM; ++j) pm = fmaxf(pm, pv[j]);
#pragma unroll
    for (int j2 = 0; j2 < MM2; ++j2) {
      f32x2 e = {hmask * __builtin_amdgcn_exp2f(C_SCALE * (pv[2 * j2] - pm)),
                 hmask * __builtin_amdgcn_exp2f(C_SCALE * (pv[2 * j2 + 1] - pm))};
      e0c2[j2] = e;
    }
  }

  // ---- fold initial (outer-0) column cost factors into E2 / e0c2 ----
#pragma unroll
  for (int j2 = 0; j2 < MM2; ++j2) {
    float t0v[2], t1v[2];
#pragma unroll
    for (int half = 0; half < 2; ++half) {
      int j = 2 * j2 + half;
      float s = 0.f, cs = 0.f;
#pragma unroll
      for (int k = 0; k < MM; ++k) {
        float a = c2l[j * MM + k];
        s += a * a;
        cs += c2l[k * MM + j];
      }
      float bq = 0.125f * s;
      t0v[half] = 0.5f * (16.f / 17.f + bq) - 0.125f * cs + cs * (1.f / 136.f);
      t1v[half] = 0.5f * (1.f / 17.f + bq) - cs * (1.f / 136.f);
    }
    f32x2 f0 = {__builtin_amdgcn_exp2f(-C_SCALE * t0v[0]),
                __builtin_amdgcn_exp2f(-C_SCALE * t0v[1])};
    f32x2 f1 = {__builtin_amdgcn_exp2f(-C_SCALE * t1v[0]),
                __builtin_amdgcn_exp2f(-C_SCALE * t1v[1])};
    e0c2[j2] *= f0;
#pragma unroll
    for (int k = 0; k < NNR; ++k) E2[k][j2] *= f1;
  }

  float g0_[MM];
#pragma unroll
  for (int j = 0; j < MM; ++j) g0_[j] = 1.f / 136.f;

  f32x2 v2[MM2];
  float u0, ureg[NNR];

  for (int outer = 0; outer < 4; ++outer) {
#pragma unroll
    for (int j2 = 0; j2 < MM2; ++j2) { f32x2 one = {1.f, 1.f}; v2[j2] = one; }
    // stabilized plain Sinkhorn; u' = rcp(Kv), v = (Q/P)*rcp(K^T u')
    for (int it = 0; it < 10; ++it) {
      f32x2 a0 = {(float)h, 0.f};         // lane1: e0c=0 -> kv0=1 -> u0 finite
#pragma unroll
      for (int j2 = 0; j2 < MM2; ++j2) a0 += e0c2[j2] * v2[j2];
      u0 = __builtin_amdgcn_rcpf(a0.x + a0.y);
#pragma unroll
      for (int k = 0; k < NNR; ++k) {
        f32x2 a = E2[k][0] * v2[0];
#pragma unroll
        for (int j2 = 1; j2 < MM2; ++j2) a += E2[k][j2] * v2[j2];
        ureg[k] = __builtin_amdgcn_rcpf(a.x + a.y);
      }
      f32x2 part2[MM2];
#pragma unroll
      for (int j2 = 0; j2 < MM2; ++j2) part2[j2] = e0c2[j2] * u0;
#pragma unroll
      for (int k = 0; k < NNR; ++k) {
        float uk = ureg[k];
#pragma unroll
        for (int j2 = 0; j2 < MM2; ++j2) part2[j2] += E2[k][j2] * uk;
      }
#pragma unroll
      for (int j2 = 0; j2 < MM2; ++j2) {
        part2[j2].x += __shfl_xor(part2[j2].x, 16);
        part2[j2].y += __shfl_xor(part2[j2].y, 16);
      }
#pragma unroll
      for (int j2 = 0; j2 < MM2; ++j2) {
        f32x2 r = {__builtin_amdgcn_rcpf(part2[j2].x),
                   __builtin_amdgcn_rcpf(part2[j2].y)};
        v2[j2] = QVP * r;
      }
    }
    // new row-0 marginal of G
    float g0n[MM];
#pragma unroll
    for (int j2 = 0; j2 < MM2; ++j2) {
      f32x2 e0u = e0c2[j2] * u0;
      e0u.x += __shfl_xor(e0u.x, 16);
      e0u.y += __shfl_xor(e0u.y, 16);
      g0n[2 * j2]     = PP * v2[j2].x * e0u.x;
      g0n[2 * j2 + 1] = PP * v2[j2].y * e0u.y;
    }
    if (outer < 3) {
      // re-linearize: multiply in the cost-delta column factors exp2(+/-C*dgd)
      float dg[MM];
#pragma unroll
      for (int j = 0; j < MM; ++j) dg[j] = g0n[j] - g0_[j];
#pragma unroll
      for (int j2 = 0; j2 < MM2; ++j2) {
        float av[2];
#pragma unroll
        for (int half = 0; half < 2; ++half) {
          int j = 2 * j2 + half;
          float d = 0.f;
#pragma unroll
          for (int k = 0; k < MM; ++k) d += dg[k] * c2l[k * MM + j];
          av[half] = C_SCALE * d;
        }
        f32x2 cfp = {__builtin_amdgcn_exp2f(av[0]), __builtin_amdgcn_exp2f(av[1])};
        f32x2 cfm = {__builtin_amdgcn_exp2f(-av[0]), __builtin_amdgcn_exp2f(-av[1])};
        e0c2[j2] *= cfm;
#pragma unroll
        for (int k = 0; k < NNR; ++k) E2[k][j2] *= cfp;
      }
    }
#pragma unroll
    for (int j = 0; j < MM; ++j) g0_[j] = g0n[j];
  }

  // ---------------- final fgw = sum G .* (Mh + 0.5*tens(G)) ----------------
  float T0p[MM];
  float tens1 = 0.f;
#pragma unroll
  for (int j = 0; j < MM; ++j) {
    float s = 0.f, cs = 0.f, gd = 0.f;
#pragma unroll
    for (int k = 0; k < MM; ++k) {
      float a = c2l[j * MM + k];
      s += a * a;
      cs += c2l[k * MM + j];
      gd += g0_[k] * c2l[k * MM + j];
    }
    float bq = 0.125f * s;
    T0p[j] = 0.5f * (16.f / 17.f + bq) - 0.125f * cs + gd;
    float T1p = 0.5f * (1.f / 17.f + bq) - gd;
    tens1 += (0.125f - g0_[j]) * T1p;
  }
  // my regular rows: G[k][j] = PP*u'[k]*E[k][j]*v[j]; Mh = hh - pv (re-gather)
  float fgr = 0.f;
#pragma unroll
  for (int k = 0; k < NNR; ++k) {
    int idx = nb[k];
    float4 p0 = Pb[(size_t)idx * 32 + t * 2];
    float4 p1 = Pb[(size_t)idx * 32 + t * 2 + 1];
    float pv[MM] = {p0.x, p0.y, p0.z, p0.w, p1.x, p1.y, p1.z, p1.w};
    float hh = 0.5f * (sqn[idx] + 1.0f);
    f32x2 acc = {0.f, 0.f};
#pragma unroll
    for (int j2 = 0; j2 < MM2; ++j2) {
      f32x2 mh = {hh - pv[2 * j2], hh - pv[2 * j2 + 1]};
      acc += (E2[k][j2] * v2[j2]) * mh;
    }
    fgr += ureg[k] * (acc.x + acc.y);
  }
  float fg = PP * fgr;
  {  // lane0-only: center row + structure-constant part over rows>=1
    float4 p0 = Pb[(size_t)node * 32 + t * 2];
    float4 p1 = Pb[(size_t)node * 32 + t * 2 + 1];
    float pv[MM] = {p0.x, p0.y, p0.z, p0.w, p1.x, p1.y, p1.z, p1.w};
    float hh0 = 0.5f * (sqn[node] + 1.0f);
    float r0 = 0.f;
#pragma unroll
    for (int j = 0; j < MM; ++j) r0 += g0_[j] * (hh0 - pv[j] + T0p[j]);
    fg += hmask * (r0 + tens1);
  }
  fg += __shfl_xor(fg, 16);
  if (h == 0) out[node * TT + t] = fg;
}

extern "C" void kernel_launch(void* const* d_in, const int* in_sizes, int n_in,
                              void* d_out, int out_size, void* d_ws, size_t ws_size,
                              hipStream_t stream) {
  const float* x  = (const float*)d_in[0];
  const int*   ei = (const int*)d_in[1];
  const float* tf = (const float*)d_in[2];
  const float* c2 = (const float*)d_in[3];
  const int* dstRow = ei + (in_sizes[1] / 2);   // row 1 of edge_index [2, N*DEG]
  int n_nodes = in_sizes[0] / 64;               // 20000

  float* P   = (float*)d_ws;                    // [n_nodes][128]
  float* sqn = P + (size_t)n_nodes * 128;       // [n_nodes]
  float* out = (float*)d_out;

  int threadsA = n_nodes * 16;
  precomp<<<(threadsA + 255) / 256, 256, 0, stream>>>(x, tf, P, sqn);
  int lanesB = out_size * 2;                    // 2 lanes per problem
  ltfgw_main<<<(lanesB + 255) / 256, 256, 0, stream>>>(P, sqn, dstRow, c2, out);
}